// Round 2
// 490.571 us; speedup vs baseline: 1.2058x; 1.2058x over previous
//
#include <hip/hip_runtime.h>
#include <math.h>

// Sinkhorn divergence (geomloss 'sinkhorn', debias=True) with quaternion
// geodesic cost, B=8, P=2048, D=4.
//
// R13 = R12 (u8 cost cache, all four mats: Cxy,Cyx,Cxx,Cyy = 128 MiB,
// L3-resident) with the diagonal handling made cancellation-free. R12's NaN:
// at eps<=1.5e-4, dfac=expm1(-C_diag/eps) rounds to exactly -1.0f, and the
// post-reduce correction fmaf(d,dfac,sv) = sv - d suffered catastrophic
// cancellation (sv ~= d + S_off with reduction rounding O(d*2^-24)),
// yielding sv <= 0 -> log2 -> NaN/-inf in f_aa/g_bb on the final passes.
// Fix: positive-terms-only diag handling:
//   * precompute forces the diag byte of mats m>=2 to code 255 (cost = pi),
//     so the decoded diag term is exp2(h-mh)*exp(-pi/eps) >= 0;
//   * pass adds the residual exact term exp2(h_i - mh + ldfac),
//     ldfac = log2(exp(-C_diag/eps) - exp(-pi/eps)) computed on host in
//     double (always > 0; no device-side subtraction anywhere);
//   * safety-net re-sweep includes (Hs[i]+ldfac) as a max candidate so the
//     recentered correction cannot overflow. sv is a sum of positives ->
//     never NaN; inf/underflow caught by the proven good-band re-sweep.
// u8 decode err <= pi/510 = 6.2e-3/elem, zero-mean across the 2048-col
// softmin argmin selection (unique argmin within one step: nn-gap ~0.06 >>
// step 0.0123) -> averages to ~1e-4 in the loss. Diag is exact.
// Tiered: n_mats in {4,3,2,1,0} by ws_size; missing mats use the proven R10
// recompute path (which computes the diag exactly via the u>=1e-6 clip).
// Packing: dword at (row*512 + t*64 + lane) packs cols (j, j+512, j+1024,
// j+1536), j = t*64+lane -- coalesced 256B/wave global access, conflict-free
// LDS Hs reads in decode and Pts reads in precompute.

#define BATCH 8
#define NP    2048
#define NPOT  (BATCH * NP)                    // 16384 floats per potential
#define MAT_ELEMS  ((size_t)BATCH * NP * NP)  // 33,554,432 u8 per matrix
#define MAT_DWORDS (MAT_ELEMS / 4)            // 8,388,608 dwords
#define MAT_BYTES  (MAT_ELEMS)                // 33,554,432 bytes (32 MiB)

__device__ __forceinline__ float bcastf(float v) {
  return __int_as_float(__builtin_amdgcn_readfirstlane(__float_as_int(v)));
}

__device__ __forceinline__ unsigned int qcode(
    float qx, float qy, float qz, float qw, float4 p,
    float P0, float P1, float P2, float P3)
{
  const float dt = fmaf(qx, p.x, fmaf(qy, p.y, fmaf(qz, p.z, qw * p.w)));
  const float u  = fmaxf(1.0f - fabsf(dt), 1e-6f);
  const float sq = __builtin_amdgcn_sqrtf(u);
  const float g  = fmaf(fmaf(fmaf(P3, u, P2), u, P1), u, P0);
  return (unsigned int)fmaf(sq, g, 0.5f);   // <= 255
}

// ---------------------------------------------------------------------------
// Precompute: C as u8 codes a = round(2*acos(|<q,p>|) * 255/pi).
// m=0: rows=x cols=y (Cxy); m=1: rows=y cols=x (Cyx);
// m=2: rows=x cols=x (Cxx); m=3: rows=y cols=y (Cyy).
// For m>=2 the diagonal byte is forced to 255 (cost = pi); the pass kernel
// adds the exact diag residual in closed form (see header comment).
// P0..P3 = acos-poly coeffs * 2 * 255/pi (scale folded in).
// ---------------------------------------------------------------------------
__global__ __launch_bounds__(512, 8) void precompute_mats(
    const float* __restrict__ x, const float* __restrict__ y,
    unsigned int* __restrict__ mats,
    float P0, float P1, float P2, float P3)
{
  const int bid  = blockIdx.x;          // grid = n_mats * 256
  const int m    = bid >> 8;
  const int b    = (bid >> 5) & 7;
  const int rg   = bid & 31;
  const int tid  = threadIdx.x;
  const int lane = tid & 63;

  __shared__ float4 Pts[NP];

  const float4* rowp; const float4* colp;
  if (m == 0)      { rowp = (const float4*)x; colp = (const float4*)y; }
  else if (m == 1) { rowp = (const float4*)y; colp = (const float4*)x; }
  else if (m == 2) { rowp = (const float4*)x; colp = (const float4*)x; }
  else             { rowp = (const float4*)y; colp = (const float4*)y; }
  rowp += b * NP; colp += b * NP;

  #pragma unroll
  for (int t = 0; t < 4; ++t)
    Pts[tid + t * 512] = colp[tid + t * 512];
  __syncthreads();

  const int wvu = __builtin_amdgcn_readfirstlane(tid >> 6);
  const int i0  = rg * 64 + wvu * 8;
  const bool dg = (m >= 2);
  float qx[8], qy[8], qz[8], qw[8];
  #pragma unroll
  for (int r = 0; r < 8; ++r) {
    const float4 t4 = rowp[i0 + r];
    qx[r] = bcastf(t4.x); qy[r] = bcastf(t4.y);
    qz[r] = bcastf(t4.z); qw[r] = bcastf(t4.w);
  }

  unsigned int* obase = mats + (size_t)m * MAT_DWORDS
                      + (((size_t)(b * NP + i0)) << 9);

  for (int t = 0; t < 8; ++t) {
    const int j = t * 64 + lane;
    const float4 p0 = Pts[j];
    const float4 p1 = Pts[j + 512];
    const float4 p2 = Pts[j + 1024];
    const float4 p3 = Pts[j + 1536];
    #pragma unroll
    for (int r = 0; r < 8; ++r) {
      const unsigned int a0 = qcode(qx[r], qy[r], qz[r], qw[r], p0, P0, P1, P2, P3);
      const unsigned int a1 = qcode(qx[r], qy[r], qz[r], qw[r], p1, P0, P1, P2, P3);
      const unsigned int a2 = qcode(qx[r], qy[r], qz[r], qw[r], p2, P0, P1, P2, P3);
      const unsigned int a3 = qcode(qx[r], qy[r], qz[r], qw[r], p3, P0, P1, P2, P3);
      unsigned int pack = a0 | (a1 << 8) | (a2 << 16) | (a3 << 24);
      if (dg) {
        const int c = i0 + r;              // diag column for this row
        if (j == (c & 511))
          pack |= 0xFFu << ((c >> 9) << 3);  // diag code is 0 -> OR sets 255
      }
      obase[(r << 9) + j] = pack;
    }
  }
}

// ---------------------------------------------------------------------------
// Pass kernel: s < n_mats -> u8 decode path; else R10 recompute path.
// ---------------------------------------------------------------------------
__global__ __launch_bounds__(512, 8) void sink_pass_r13(
    const float* __restrict__ x, const float* __restrict__ y,
    const float* __restrict__ wx, const float* __restrict__ wy,
    const unsigned int* __restrict__ mats, int n_mats,
    const float* __restrict__ pot_old, float* __restrict__ pot_new,
    float eps, float c1 /* log2e/eps, 0 on init */,
    float seed_s /* -log2e/eps, 0 on init */,
    float kdec /* (pi/255)*log2e/eps */,
    float ldfac /* log2(exp(-C_diag/eps) - exp(-pi/eps)), diag residual */,
    float B0, float B1, float B2, float B3 /* acos(u)-poly * 2*log2e/eps */,
    int use_avg)
{
  const int bid  = blockIdx.x;         // grid 1024: s(4) x b(8) x rg(32)
  const int s    = bid >> 8;
  const int b    = (bid >> 5) & 7;
  const int rg   = bid & 31;
  const int tid  = threadIdx.x;
  const int lane = tid & 63;

  __shared__ float4 Pts[NP];   // 32 KB (recompute path only)
  __shared__ float  Hs[NP];    //  8 KB

  const float4* colp; const float* colw; const float* colpot; const float4* rowp;
  if (s == 0)      { colp=(const float4*)y; colw=wy; colpot=pot_old+1*NPOT; rowp=(const float4*)x; }
  else if (s == 1) { colp=(const float4*)x; colw=wx; colpot=pot_old+0*NPOT; rowp=(const float4*)y; }
  else if (s == 2) { colp=(const float4*)x; colw=wx; colpot=pot_old+2*NPOT; rowp=(const float4*)x; }
  else             { colp=(const float4*)y; colw=wy; colpot=pot_old+3*NPOT; rowp=(const float4*)y; }
  colp += b * NP; colw += b * NP; colpot += b * NP;

  const bool use_mat = (s < n_mats);
  const bool do_diag = use_mat && (s >= 2);

  if (use_mat) {
    #pragma unroll
    for (int t = 0; t < 4; ++t) {
      const int idx = tid + t * 512;
      Hs[idx] = fmaf(colpot[idx], c1, __builtin_amdgcn_logf(colw[idx]));
    }
  } else {
    #pragma unroll
    for (int t = 0; t < 4; ++t) {
      const int idx = tid + t * 512;
      Pts[idx] = colp[idx];
      Hs[idx] = fmaf(colpot[idx], c1, __builtin_amdgcn_logf(colw[idx]));
    }
  }
  __syncthreads();

  const int wvu = __builtin_amdgcn_readfirstlane(tid >> 6);
  const int i0  = rg * 64 + wvu * 8;
  const int oidx = s * NPOT + b * NP + i0;
  float mh[8];
  #pragma unroll
  for (int r = 0; r < 8; ++r)
    mh[r] = bcastf(pot_old[oidx + r] * seed_s);

  float ss[8] = {0.f, 0.f, 0.f, 0.f, 0.f, 0.f, 0.f, 0.f};

  if (use_mat) {
    // ---------------- u8 decode path ----------------
    const unsigned int* mrow = mats + (size_t)s * MAT_DWORDS
                             + (((size_t)(b * NP + i0)) << 9);
    for (int t = 0; t < 8; ++t) {
      const int j = t * 64 + lane;
      const float h0 = Hs[j];
      const float h1 = Hs[j + 512];
      const float h2 = Hs[j + 1024];
      const float h3 = Hs[j + 1536];
      #pragma unroll
      for (int r = 0; r < 8; ++r) {
        const unsigned int U = mrow[(r << 9) + j];
        const float a0 = (float)(U & 0xFFu);          // v_cvt_f32_ubyte0
        const float a1 = (float)((U >> 8) & 0xFFu);   // v_cvt_f32_ubyte1
        const float a2 = (float)((U >> 16) & 0xFFu);  // v_cvt_f32_ubyte2
        const float a3 = (float)(U >> 24);            // v_cvt_f32_ubyte3
        ss[r] += __builtin_amdgcn_exp2f(fmaf(a0, -kdec, h0 - mh[r]))
               + __builtin_amdgcn_exp2f(fmaf(a1, -kdec, h1 - mh[r]))
               + __builtin_amdgcn_exp2f(fmaf(a2, -kdec, h2 - mh[r]))
               + __builtin_amdgcn_exp2f(fmaf(a3, -kdec, h3 - mh[r]));
      }
    }
    #pragma unroll
    for (int r = 0; r < 8; ++r) {
      float sv = ss[r];
      #pragma unroll
      for (int off = 32; off >= 1; off >>= 1)
        sv += __shfl_xor(sv, off, 64);
      // exact-diag residual (positive add; decoded diag carried cost=pi):
      //   exp2(h_i - mh + ldfac), ldfac = log2(exp(-Cd/eps) - exp(-pi/eps))
      if (do_diag)
        sv += __builtin_amdgcn_exp2f(Hs[i0 + r] - mh[r] + ldfac);
      ss[r] = sv;
    }
    // safety net: two-phase decode re-sweep for out-of-band rows
    #pragma unroll
    for (int r = 0; r < 8; ++r) {
      const bool good = (ss[r] >= 8.6736174e-19f) && (ss[r] <= 1.1529215e18f);
      if (!good) {
        float mv = -3.0e38f;
        for (int t = 0; t < 8; ++t) {
          const int j = t * 64 + lane;
          const unsigned int U = mrow[(r << 9) + j];
          mv = fmaxf(mv, fmaf((float)(U & 0xFFu),         -kdec, Hs[j]));
          mv = fmaxf(mv, fmaf((float)((U >> 8) & 0xFFu),  -kdec, Hs[j + 512]));
          mv = fmaxf(mv, fmaf((float)((U >> 16) & 0xFFu), -kdec, Hs[j + 1024]));
          mv = fmaxf(mv, fmaf((float)(U >> 24),           -kdec, Hs[j + 1536]));
        }
        #pragma unroll
        for (int off = 32; off >= 1; off >>= 1)
          mv = fmaxf(mv, __shfl_xor(mv, off, 64));
        if (do_diag) mv = fmaxf(mv, Hs[i0 + r] + ldfac);  // diag candidate
        mh[r] = mv;
        float sv = 0.0f;
        for (int t = 0; t < 8; ++t) {
          const int j = t * 64 + lane;
          const unsigned int U = mrow[(r << 9) + j];
          sv += __builtin_amdgcn_exp2f(fmaf((float)(U & 0xFFu),         -kdec, Hs[j]        - mv))
              + __builtin_amdgcn_exp2f(fmaf((float)((U >> 8) & 0xFFu),  -kdec, Hs[j + 512]  - mv))
              + __builtin_amdgcn_exp2f(fmaf((float)((U >> 16) & 0xFFu), -kdec, Hs[j + 1024] - mv))
              + __builtin_amdgcn_exp2f(fmaf((float)(U >> 24),           -kdec, Hs[j + 1536] - mv));
        }
        #pragma unroll
        for (int off = 32; off >= 1; off >>= 1)
          sv += __shfl_xor(sv, off, 64);
        if (do_diag)
          sv += __builtin_amdgcn_exp2f(Hs[i0 + r] + ldfac - mv);  // <= 1
        ss[r] = sv;
      }
    }
  } else {
    // ---------------- R10 recompute path (proven) ----------------
    float qx[8], qy[8], qz[8], qw[8];
    #pragma unroll
    for (int r = 0; r < 8; ++r) {
      const float4 t4 = rowp[b * NP + i0 + r];
      qx[r] = bcastf(t4.x); qy[r] = bcastf(t4.y);
      qz[r] = bcastf(t4.z); qw[r] = bcastf(t4.w);
    }
    for (int t = 0; t < 16; ++t) {
      float4 p[2]; float h[2];
      #pragma unroll
      for (int cc = 0; cc < 2; ++cc) {
        const int j = (t * 2 + cc) * 64 + lane;
        p[cc] = Pts[j];
        h[cc] = Hs[j];
      }
      #pragma unroll
      for (int r = 0; r < 8; ++r) {
        #pragma unroll
        for (int cc = 0; cc < 2; ++cc) {
          const float dt = fmaf(qx[r], p[cc].x,
                            fmaf(qy[r], p[cc].y,
                             fmaf(qz[r], p[cc].z, qw[r] * p[cc].w)));
          const float u  = fmaxf(1.0f - fabsf(dt), 1e-6f);
          const float sq = __builtin_amdgcn_sqrtf(u);
          const float pl = fmaf(fmaf(fmaf(B3, u, B2), u, B1), u, B0);
          const float v  = fmaf(sq, -pl, h[cc]);
          ss[r] += __builtin_amdgcn_exp2f(v - mh[r]);
        }
      }
    }
    #pragma unroll
    for (int r = 0; r < 8; ++r) {
      float sv = ss[r];
      #pragma unroll
      for (int off = 32; off >= 1; off >>= 1)
        sv += __shfl_xor(sv, off, 64);
      ss[r] = sv;
    }
    #pragma unroll
    for (int r = 0; r < 8; ++r) {
      const bool good = (ss[r] >= 8.6736174e-19f) && (ss[r] <= 1.1529215e18f);
      if (!good) {
        float mv = -3.0e38f;
        for (int t = 0; t < 32; ++t) {
          const int j = t * 64 + lane;
          const float4 p = Pts[j];
          const float dt = fmaf(qx[r], p.x,
                            fmaf(qy[r], p.y, fmaf(qz[r], p.z, qw[r] * p.w)));
          const float u  = fmaxf(1.0f - fabsf(dt), 1e-6f);
          const float sq = __builtin_amdgcn_sqrtf(u);
          const float pl = fmaf(fmaf(fmaf(B3, u, B2), u, B1), u, B0);
          mv = fmaxf(mv, fmaf(sq, -pl, Hs[j]));
        }
        #pragma unroll
        for (int off = 32; off >= 1; off >>= 1)
          mv = fmaxf(mv, __shfl_xor(mv, off, 64));
        mh[r] = mv;
        float sv = 0.0f;
        for (int t = 0; t < 32; ++t) {
          const int j = t * 64 + lane;
          const float4 p = Pts[j];
          const float dt = fmaf(qx[r], p.x,
                            fmaf(qy[r], p.y, fmaf(qz[r], p.z, qw[r] * p.w)));
          const float u  = fmaxf(1.0f - fabsf(dt), 1e-6f);
          const float sq = __builtin_amdgcn_sqrtf(u);
          const float pl = fmaf(fmaf(fmaf(B3, u, B2), u, B1), u, B0);
          sv += __builtin_amdgcn_exp2f(fmaf(sq, -pl, Hs[j]) - mh[r]);
        }
        #pragma unroll
        for (int off = 32; off >= 1; off >>= 1)
          sv += __shfl_xor(sv, off, 64);
        ss[r] = sv;
      }
    }
  }

  if (lane == 0) {
    #pragma unroll
    for (int r = 0; r < 8; ++r) {
      float res = -eps * 0.69314718055994531f
                * (mh[r] + __builtin_amdgcn_logf(ss[r]));
      if (use_avg) res = 0.5f * (pot_old[oidx + r] + res);
      pot_new[oidx + r] = res;
    }
  }
}

__global__ __launch_bounds__(256) void loss_kernel(
    const float* __restrict__ pot, const float* __restrict__ wx,
    const float* __restrict__ wy, float* __restrict__ out)
{
  const int tid = threadIdx.x;
  double acc = 0.0;
  for (int idx = tid; idx < NPOT; idx += 256) {
    acc += (double)wx[idx] * ((double)pot[0 * NPOT + idx] - (double)pot[2 * NPOT + idx]);
    acc += (double)wy[idx] * ((double)pot[1 * NPOT + idx] - (double)pot[3 * NPOT + idx]);
  }
  #pragma unroll
  for (int off = 32; off >= 1; off >>= 1)
    acc += __shfl_xor(acc, off, 64);
  __shared__ double wsum[4];
  if ((tid & 63) == 0) wsum[tid >> 6] = acc;
  __syncthreads();
  if (tid == 0)
    out[0] = (float)((wsum[0] + wsum[1] + wsum[2] + wsum[3]) / (double)BATCH);
}

extern "C" void kernel_launch(void* const* d_in, const int* in_sizes, int n_in,
                              void* d_out, int out_size, void* d_ws, size_t ws_size,
                              hipStream_t stream)
{
  const float* x  = (const float*)d_in[0];
  const float* y  = (const float*)d_in[1];
  const float* wx = (const float*)d_in[2];
  const float* wy = (const float*)d_in[3];

  const size_t potBytes = (size_t)2 * 4 * NPOT * 4;   // 524,288
  int n_mats = 0;
  if      (ws_size >= 4 * MAT_BYTES + potBytes) n_mats = 4;
  else if (ws_size >= 3 * MAT_BYTES + potBytes) n_mats = 3;
  else if (ws_size >= 2 * MAT_BYTES + potBytes) n_mats = 2;
  else if (ws_size >= 1 * MAT_BYTES + potBytes) n_mats = 1;

  unsigned int* mats = (unsigned int*)d_ws;
  float* pot[2];
  pot[0] = (float*)((char*)d_ws + (size_t)n_mats * MAT_BYTES);
  pot[1] = pot[0] + 4 * NPOT;

  // geomloss epsilon_schedule(p=2, diameter=3.15, blur=0.01, scaling=0.5)
  double eps_list[16]; int ne = 0;
  eps_list[ne++] = 3.15 * 3.15;
  const double stop = 2.0 * log(0.01), step = 2.0 * log(0.5);
  for (double e = 2.0 * log(3.15); e > stop; e += step) eps_list[ne++] = exp(e);
  eps_list[ne++] = 0.01 * 0.01;   // ne == 11

  const double LOG2E = 1.4426950408889634;
  const double PI    = 3.14159265358979323846;
  // acos(d) ~= sqrt(u)*(b0 + b1 u + b2 u^2 + b3 u^3), u = 1-d, |err|<=6.7e-5
  const double b0 = 1.4141461, b1 = 0.1197803, b2 = 0.0180731, b3 = 0.0187293;
  const double cdiag = 2.0 * acos(1.0 - 1e-6);   // exact diag cost 2.8284e-3
  const dim3 grid(1024), blkPass(512), blkLoss(256);
  int cur = 0;

  if (n_mats > 0) {
    const double S2 = 2.0 * 255.0 / PI;   // fold 2*255/pi into coeffs
    hipLaunchKernelGGL(precompute_mats, dim3(n_mats * 256), blkPass, 0, stream,
        x, y, mats,
        (float)(b0 * S2), (float)(b1 * S2), (float)(b2 * S2), (float)(b3 * S2));
  }

  auto launch_pass = [&](double e, float c1f, float seedf, int avg) {
    const double sc = 2.0 * LOG2E / e;
    const double kd = (PI / 255.0) * (LOG2E / e);
    // diag residual factor: exact exp(-Cd/e) minus decoded exp(-pi/e); > 0.
    const double efac = exp(-cdiag / e) - exp(-PI / e);
    const double ldf  = log(efac) * LOG2E;
    hipLaunchKernelGGL(sink_pass_r13, grid, blkPass, 0, stream,
        x, y, wx, wy, mats, n_mats, pot[cur], pot[1 - cur],
        (float)e, c1f, seedf, (float)kd, (float)ldf,
        (float)(b0 * sc), (float)(b1 * sc), (float)(b2 * sc), (float)(b3 * sc), avg);
    cur ^= 1;
  };

  // init pass: no potential in h, m_hat = 0, replace-mode
  launch_pass(eps_list[0], 0.0f, 0.0f, 0);
  // annealing loop, averaging update
  for (int k = 0; k < ne; ++k) {
    const double e = eps_list[k];
    launch_pass(e, (float)(LOG2E / e), (float)(-LOG2E / e), 1);
  }
  // final extrapolation, replace-mode
  {
    const double e = eps_list[ne - 1];
    launch_pass(e, (float)(LOG2E / e), (float)(-LOG2E / e), 0);
  }

  hipLaunchKernelGGL(loss_kernel, dim3(1), blkLoss, 0, stream,
      pot[cur], wx, wy, (float*)d_out);
}

// Round 3
// 487.904 us; speedup vs baseline: 1.2124x; 1.0055x over previous
//
#include <hip/hip_runtime.h>
#include <math.h>

// Sinkhorn divergence (geomloss 'sinkhorn', debias=True) with quaternion
// geodesic cost, B=8, P=2048, D=4.
//
// R14 = R13 with precompute FUSED into the init pass. R13 counters showed:
//   * pass 0 at 134 us (vs ~25 us steady): init pass read POISONED pot_old
//     (mh = poison*0 = NaN for NaN-pattern poison) -> ss=NaN -> good-band
//     fail for every row -> 8x serialized safety-net re-sweeps (3x work,
//     VALUBusy 3.1%, +68MB fetch). Fix: init kernel takes NO pot input;
//     mh=0 and Hs=log2(w) directly.
//   * precompute_mats (56 us, VALUBusy 81%) duplicates the exact cost
//     evaluations the init pass performs: slice s of the pass is matrix m=s.
//     Fix: sink_init_fused computes u8 codes once, stores them (s<n_mats),
//     and feeds the decoded codes to its own softmin (mh=0) -- numerically
//     identical to R13's precompute->decode-pass sequence.
// Diag handling (proven in R13, cancellation-free): symmetric mats force the
// diag byte to 255 (cost=pi) and every consumer adds the positive residual
// exp2(h_i - mh + ldfac), ldfac = log2(exp(-Cd/eps)-exp(-pi/eps)) from host.
// Init safety net uses the full-precision recompute from LDS Pts (B-coeffs),
// independent of the just-written mats (no same-kernel RAW on global).
// Steady passes (sink_pass_r13 logic, unchanged): u8 decode for s<n_mats,
// R10 recompute otherwise. Tiered n_mats in {4,3,2,1,0} by ws_size.
// Packing: dword at (row*512 + t*64 + lane) packs cols (j, j+512, j+1024,
// j+1536), j = t*64+lane -- coalesced global access, conflict-free LDS reads.

#define BATCH 8
#define NP    2048
#define NPOT  (BATCH * NP)                    // 16384 floats per potential
#define MAT_ELEMS  ((size_t)BATCH * NP * NP)  // 33,554,432 u8 per matrix
#define MAT_DWORDS (MAT_ELEMS / 4)            // 8,388,608 dwords
#define MAT_BYTES  (MAT_ELEMS)                // 33,554,432 bytes (32 MiB)

__device__ __forceinline__ float bcastf(float v) {
  return __int_as_float(__builtin_amdgcn_readfirstlane(__float_as_int(v)));
}

__device__ __forceinline__ unsigned int qcode(
    float qx, float qy, float qz, float qw, float4 p,
    float P0, float P1, float P2, float P3)
{
  const float dt = fmaf(qx, p.x, fmaf(qy, p.y, fmaf(qz, p.z, qw * p.w)));
  const float u  = fmaxf(1.0f - fabsf(dt), 1e-6f);
  const float sq = __builtin_amdgcn_sqrtf(u);
  const float g  = fmaf(fmaf(fmaf(P3, u, P2), u, P1), u, P0);
  return (unsigned int)fmaf(sq, g, 0.5f);   // <= 255
}

// ---------------------------------------------------------------------------
// Fused init pass: computes u8 codes a = round(2*acos(|<q,p>|)*255/pi),
// stores them for s < n_mats, and computes the init softmin (mh=0,
// Hs=log2(w)) from the decoded codes. Replace-mode output. No pot input.
// s=0: rows=x cols=y (Cxy); s=1: rows=y cols=x (Cyx);
// s=2: rows=x cols=x (Cxx); s=3: rows=y cols=y (Cyy).
// P0..P3 = acos-poly * 2*255/pi (code scale); B0..B3 = acos-poly * 2*log2e/eps
// (safety-net scale); kdec = (pi/255)*log2e/eps; ldfac = diag residual.
// ---------------------------------------------------------------------------
__global__ __launch_bounds__(512, 8) void sink_init_fused(
    const float* __restrict__ x, const float* __restrict__ y,
    const float* __restrict__ wx, const float* __restrict__ wy,
    unsigned int* __restrict__ mats, int n_mats,
    float* __restrict__ pot_new,
    float eps, float kdec, float ldfac,
    float P0, float P1, float P2, float P3,
    float B0, float B1, float B2, float B3)
{
  const int bid  = blockIdx.x;         // grid 1024: s(4) x b(8) x rg(32)
  const int s    = bid >> 8;
  const int b    = (bid >> 5) & 7;
  const int rg   = bid & 31;
  const int tid  = threadIdx.x;
  const int lane = tid & 63;

  __shared__ float4 Pts[NP];   // 32 KB
  __shared__ float  Hs[NP];    //  8 KB

  const float4* colp; const float* colw; const float4* rowp;
  if (s == 0)      { colp=(const float4*)y; colw=wy; rowp=(const float4*)x; }
  else if (s == 1) { colp=(const float4*)x; colw=wx; rowp=(const float4*)y; }
  else if (s == 2) { colp=(const float4*)x; colw=wx; rowp=(const float4*)x; }
  else             { colp=(const float4*)y; colw=wy; rowp=(const float4*)y; }
  colp += b * NP; colw += b * NP;

  #pragma unroll
  for (int t = 0; t < 4; ++t) {
    const int idx = tid + t * 512;
    Pts[idx] = colp[idx];
    Hs[idx]  = __builtin_amdgcn_logf(colw[idx]);   // log2(w); NO pot read
  }
  __syncthreads();

  const int wvu = __builtin_amdgcn_readfirstlane(tid >> 6);
  const int i0  = rg * 64 + wvu * 8;
  const int oidx = s * NPOT + b * NP + i0;
  const bool dg    = (s >= 2);
  const bool store = (s < n_mats);

  float qx[8], qy[8], qz[8], qw[8];
  #pragma unroll
  for (int r = 0; r < 8; ++r) {
    const float4 t4 = rowp[b * NP + i0 + r];
    qx[r] = bcastf(t4.x); qy[r] = bcastf(t4.y);
    qz[r] = bcastf(t4.z); qw[r] = bcastf(t4.w);
  }

  unsigned int* obase = mats + (size_t)s * MAT_DWORDS
                      + (((size_t)(b * NP + i0)) << 9);

  float mh[8];
  float ss[8];
  #pragma unroll
  for (int r = 0; r < 8; ++r) { mh[r] = 0.0f; ss[r] = 0.0f; }

  for (int t = 0; t < 8; ++t) {
    const int j = t * 64 + lane;
    const float4 p0 = Pts[j];
    const float4 p1 = Pts[j + 512];
    const float4 p2 = Pts[j + 1024];
    const float4 p3 = Pts[j + 1536];
    const float h0 = Hs[j];
    const float h1 = Hs[j + 512];
    const float h2 = Hs[j + 1024];
    const float h3 = Hs[j + 1536];
    #pragma unroll
    for (int r = 0; r < 8; ++r) {
      const unsigned int a0 = qcode(qx[r], qy[r], qz[r], qw[r], p0, P0, P1, P2, P3);
      const unsigned int a1 = qcode(qx[r], qy[r], qz[r], qw[r], p1, P0, P1, P2, P3);
      const unsigned int a2 = qcode(qx[r], qy[r], qz[r], qw[r], p2, P0, P1, P2, P3);
      const unsigned int a3 = qcode(qx[r], qy[r], qz[r], qw[r], p3, P0, P1, P2, P3);
      unsigned int pack = a0 | (a1 << 8) | (a2 << 16) | (a3 << 24);
      if (dg) {
        const int c = i0 + r;                  // diag column for this row
        if (j == (c & 511))
          pack |= 0xFFu << ((c >> 9) << 3);    // diag code 0 -> OR sets 255
      }
      if (store) obase[(r << 9) + j] = pack;
      // softmin from the decoded bytes (identical to steady decode path)
      const float f0 = (float)(pack & 0xFFu);
      const float f1 = (float)((pack >> 8) & 0xFFu);
      const float f2 = (float)((pack >> 16) & 0xFFu);
      const float f3 = (float)(pack >> 24);
      ss[r] += __builtin_amdgcn_exp2f(fmaf(f0, -kdec, h0))
             + __builtin_amdgcn_exp2f(fmaf(f1, -kdec, h1))
             + __builtin_amdgcn_exp2f(fmaf(f2, -kdec, h2))
             + __builtin_amdgcn_exp2f(fmaf(f3, -kdec, h3));
    }
  }
  #pragma unroll
  for (int r = 0; r < 8; ++r) {
    float sv = ss[r];
    #pragma unroll
    for (int off = 32; off >= 1; off >>= 1)
      sv += __shfl_xor(sv, off, 64);
    if (dg)  // exact-diag residual (positive add; decoded diag carried pi)
      sv += __builtin_amdgcn_exp2f(Hs[i0 + r] + ldfac);
    ss[r] = sv;
  }

  // safety net: full-precision recompute from Pts (independent of mats)
  #pragma unroll
  for (int r = 0; r < 8; ++r) {
    const bool good = (ss[r] >= 8.6736174e-19f) && (ss[r] <= 1.1529215e18f);
    if (!good) {
      float mv = -3.0e38f;
      for (int t = 0; t < 32; ++t) {
        const int j = t * 64 + lane;
        const float4 p = Pts[j];
        const float dt = fmaf(qx[r], p.x,
                          fmaf(qy[r], p.y, fmaf(qz[r], p.z, qw[r] * p.w)));
        const float u  = fmaxf(1.0f - fabsf(dt), 1e-6f);
        const float sq = __builtin_amdgcn_sqrtf(u);
        const float pl = fmaf(fmaf(fmaf(B3, u, B2), u, B1), u, B0);
        mv = fmaxf(mv, fmaf(sq, -pl, Hs[j]));
      }
      #pragma unroll
      for (int off = 32; off >= 1; off >>= 1)
        mv = fmaxf(mv, __shfl_xor(mv, off, 64));
      mh[r] = mv;
      float sv = 0.0f;
      for (int t = 0; t < 32; ++t) {
        const int j = t * 64 + lane;
        const float4 p = Pts[j];
        const float dt = fmaf(qx[r], p.x,
                          fmaf(qy[r], p.y, fmaf(qz[r], p.z, qw[r] * p.w)));
        const float u  = fmaxf(1.0f - fabsf(dt), 1e-6f);
        const float sq = __builtin_amdgcn_sqrtf(u);
        const float pl = fmaf(fmaf(fmaf(B3, u, B2), u, B1), u, B0);
        sv += __builtin_amdgcn_exp2f(fmaf(sq, -pl, Hs[j]) - mv);
      }
      #pragma unroll
      for (int off = 32; off >= 1; off >>= 1)
        sv += __shfl_xor(sv, off, 64);
      ss[r] = sv;
    }
  }

  if (lane == 0) {
    #pragma unroll
    for (int r = 0; r < 8; ++r)
      pot_new[oidx + r] = -eps * 0.69314718055994531f
                        * (mh[r] + __builtin_amdgcn_logf(ss[r]));
  }
}

// ---------------------------------------------------------------------------
// Steady pass: s < n_mats -> u8 decode path; else R10 recompute path.
// (unchanged from R13)
// ---------------------------------------------------------------------------
__global__ __launch_bounds__(512, 8) void sink_pass_r14(
    const float* __restrict__ x, const float* __restrict__ y,
    const float* __restrict__ wx, const float* __restrict__ wy,
    const unsigned int* __restrict__ mats, int n_mats,
    const float* __restrict__ pot_old, float* __restrict__ pot_new,
    float eps, float c1 /* log2e/eps */,
    float seed_s /* -log2e/eps */,
    float kdec /* (pi/255)*log2e/eps */,
    float ldfac /* log2(exp(-C_diag/eps) - exp(-pi/eps)) */,
    float B0, float B1, float B2, float B3 /* acos(u)-poly * 2*log2e/eps */,
    int use_avg)
{
  const int bid  = blockIdx.x;         // grid 1024: s(4) x b(8) x rg(32)
  const int s    = bid >> 8;
  const int b    = (bid >> 5) & 7;
  const int rg   = bid & 31;
  const int tid  = threadIdx.x;
  const int lane = tid & 63;

  __shared__ float4 Pts[NP];   // 32 KB (recompute path only)
  __shared__ float  Hs[NP];    //  8 KB

  const float4* colp; const float* colw; const float* colpot; const float4* rowp;
  if (s == 0)      { colp=(const float4*)y; colw=wy; colpot=pot_old+1*NPOT; rowp=(const float4*)x; }
  else if (s == 1) { colp=(const float4*)x; colw=wx; colpot=pot_old+0*NPOT; rowp=(const float4*)y; }
  else if (s == 2) { colp=(const float4*)x; colw=wx; colpot=pot_old+2*NPOT; rowp=(const float4*)x; }
  else             { colp=(const float4*)y; colw=wy; colpot=pot_old+3*NPOT; rowp=(const float4*)y; }
  colp += b * NP; colw += b * NP; colpot += b * NP;

  const bool use_mat = (s < n_mats);
  const bool do_diag = use_mat && (s >= 2);

  if (use_mat) {
    #pragma unroll
    for (int t = 0; t < 4; ++t) {
      const int idx = tid + t * 512;
      Hs[idx] = fmaf(colpot[idx], c1, __builtin_amdgcn_logf(colw[idx]));
    }
  } else {
    #pragma unroll
    for (int t = 0; t < 4; ++t) {
      const int idx = tid + t * 512;
      Pts[idx] = colp[idx];
      Hs[idx] = fmaf(colpot[idx], c1, __builtin_amdgcn_logf(colw[idx]));
    }
  }
  __syncthreads();

  const int wvu = __builtin_amdgcn_readfirstlane(tid >> 6);
  const int i0  = rg * 64 + wvu * 8;
  const int oidx = s * NPOT + b * NP + i0;
  float mh[8];
  #pragma unroll
  for (int r = 0; r < 8; ++r)
    mh[r] = bcastf(pot_old[oidx + r] * seed_s);

  float ss[8] = {0.f, 0.f, 0.f, 0.f, 0.f, 0.f, 0.f, 0.f};

  if (use_mat) {
    // ---------------- u8 decode path ----------------
    const unsigned int* mrow = mats + (size_t)s * MAT_DWORDS
                             + (((size_t)(b * NP + i0)) << 9);
    for (int t = 0; t < 8; ++t) {
      const int j = t * 64 + lane;
      const float h0 = Hs[j];
      const float h1 = Hs[j + 512];
      const float h2 = Hs[j + 1024];
      const float h3 = Hs[j + 1536];
      #pragma unroll
      for (int r = 0; r < 8; ++r) {
        const unsigned int U = mrow[(r << 9) + j];
        const float a0 = (float)(U & 0xFFu);          // v_cvt_f32_ubyte0
        const float a1 = (float)((U >> 8) & 0xFFu);   // v_cvt_f32_ubyte1
        const float a2 = (float)((U >> 16) & 0xFFu);  // v_cvt_f32_ubyte2
        const float a3 = (float)(U >> 24);            // v_cvt_f32_ubyte3
        ss[r] += __builtin_amdgcn_exp2f(fmaf(a0, -kdec, h0 - mh[r]))
               + __builtin_amdgcn_exp2f(fmaf(a1, -kdec, h1 - mh[r]))
               + __builtin_amdgcn_exp2f(fmaf(a2, -kdec, h2 - mh[r]))
               + __builtin_amdgcn_exp2f(fmaf(a3, -kdec, h3 - mh[r]));
      }
    }
    #pragma unroll
    for (int r = 0; r < 8; ++r) {
      float sv = ss[r];
      #pragma unroll
      for (int off = 32; off >= 1; off >>= 1)
        sv += __shfl_xor(sv, off, 64);
      if (do_diag)
        sv += __builtin_amdgcn_exp2f(Hs[i0 + r] - mh[r] + ldfac);
      ss[r] = sv;
    }
    // safety net: two-phase decode re-sweep for out-of-band rows
    #pragma unroll
    for (int r = 0; r < 8; ++r) {
      const bool good = (ss[r] >= 8.6736174e-19f) && (ss[r] <= 1.1529215e18f);
      if (!good) {
        float mv = -3.0e38f;
        for (int t = 0; t < 8; ++t) {
          const int j = t * 64 + lane;
          const unsigned int U = mrow[(r << 9) + j];
          mv = fmaxf(mv, fmaf((float)(U & 0xFFu),         -kdec, Hs[j]));
          mv = fmaxf(mv, fmaf((float)((U >> 8) & 0xFFu),  -kdec, Hs[j + 512]));
          mv = fmaxf(mv, fmaf((float)((U >> 16) & 0xFFu), -kdec, Hs[j + 1024]));
          mv = fmaxf(mv, fmaf((float)(U >> 24),           -kdec, Hs[j + 1536]));
        }
        #pragma unroll
        for (int off = 32; off >= 1; off >>= 1)
          mv = fmaxf(mv, __shfl_xor(mv, off, 64));
        if (do_diag) mv = fmaxf(mv, Hs[i0 + r] + ldfac);  // diag candidate
        mh[r] = mv;
        float sv = 0.0f;
        for (int t = 0; t < 8; ++t) {
          const int j = t * 64 + lane;
          const unsigned int U = mrow[(r << 9) + j];
          sv += __builtin_amdgcn_exp2f(fmaf((float)(U & 0xFFu),         -kdec, Hs[j]        - mv))
              + __builtin_amdgcn_exp2f(fmaf((float)((U >> 8) & 0xFFu),  -kdec, Hs[j + 512]  - mv))
              + __builtin_amdgcn_exp2f(fmaf((float)((U >> 16) & 0xFFu), -kdec, Hs[j + 1024] - mv))
              + __builtin_amdgcn_exp2f(fmaf((float)(U >> 24),           -kdec, Hs[j + 1536] - mv));
        }
        #pragma unroll
        for (int off = 32; off >= 1; off >>= 1)
          sv += __shfl_xor(sv, off, 64);
        if (do_diag)
          sv += __builtin_amdgcn_exp2f(Hs[i0 + r] + ldfac - mv);  // <= 1
        ss[r] = sv;
      }
    }
  } else {
    // ---------------- R10 recompute path (proven) ----------------
    float qx[8], qy[8], qz[8], qw[8];
    #pragma unroll
    for (int r = 0; r < 8; ++r) {
      const float4 t4 = rowp[b * NP + i0 + r];
      qx[r] = bcastf(t4.x); qy[r] = bcastf(t4.y);
      qz[r] = bcastf(t4.z); qw[r] = bcastf(t4.w);
    }
    for (int t = 0; t < 16; ++t) {
      float4 p[2]; float h[2];
      #pragma unroll
      for (int cc = 0; cc < 2; ++cc) {
        const int j = (t * 2 + cc) * 64 + lane;
        p[cc] = Pts[j];
        h[cc] = Hs[j];
      }
      #pragma unroll
      for (int r = 0; r < 8; ++r) {
        #pragma unroll
        for (int cc = 0; cc < 2; ++cc) {
          const float dt = fmaf(qx[r], p[cc].x,
                            fmaf(qy[r], p[cc].y,
                             fmaf(qz[r], p[cc].z, qw[r] * p[cc].w)));
          const float u  = fmaxf(1.0f - fabsf(dt), 1e-6f);
          const float sq = __builtin_amdgcn_sqrtf(u);
          const float pl = fmaf(fmaf(fmaf(B3, u, B2), u, B1), u, B0);
          const float v  = fmaf(sq, -pl, h[cc]);
          ss[r] += __builtin_amdgcn_exp2f(v - mh[r]);
        }
      }
    }
    #pragma unroll
    for (int r = 0; r < 8; ++r) {
      float sv = ss[r];
      #pragma unroll
      for (int off = 32; off >= 1; off >>= 1)
        sv += __shfl_xor(sv, off, 64);
      ss[r] = sv;
    }
    #pragma unroll
    for (int r = 0; r < 8; ++r) {
      const bool good = (ss[r] >= 8.6736174e-19f) && (ss[r] <= 1.1529215e18f);
      if (!good) {
        float mv = -3.0e38f;
        for (int t = 0; t < 32; ++t) {
          const int j = t * 64 + lane;
          const float4 p = Pts[j];
          const float dt = fmaf(qx[r], p.x,
                            fmaf(qy[r], p.y, fmaf(qz[r], p.z, qw[r] * p.w)));
          const float u  = fmaxf(1.0f - fabsf(dt), 1e-6f);
          const float sq = __builtin_amdgcn_sqrtf(u);
          const float pl = fmaf(fmaf(fmaf(B3, u, B2), u, B1), u, B0);
          mv = fmaxf(mv, fmaf(sq, -pl, Hs[j]));
        }
        #pragma unroll
        for (int off = 32; off >= 1; off >>= 1)
          mv = fmaxf(mv, __shfl_xor(mv, off, 64));
        mh[r] = mv;
        float sv = 0.0f;
        for (int t = 0; t < 32; ++t) {
          const int j = t * 64 + lane;
          const float4 p = Pts[j];
          const float dt = fmaf(qx[r], p.x,
                            fmaf(qy[r], p.y, fmaf(qz[r], p.z, qw[r] * p.w)));
          const float u  = fmaxf(1.0f - fabsf(dt), 1e-6f);
          const float sq = __builtin_amdgcn_sqrtf(u);
          const float pl = fmaf(fmaf(fmaf(B3, u, B2), u, B1), u, B0);
          sv += __builtin_amdgcn_exp2f(fmaf(sq, -pl, Hs[j]) - mh[r]);
        }
        #pragma unroll
        for (int off = 32; off >= 1; off >>= 1)
          sv += __shfl_xor(sv, off, 64);
        ss[r] = sv;
      }
    }
  }

  if (lane == 0) {
    #pragma unroll
    for (int r = 0; r < 8; ++r) {
      float res = -eps * 0.69314718055994531f
                * (mh[r] + __builtin_amdgcn_logf(ss[r]));
      if (use_avg) res = 0.5f * (pot_old[oidx + r] + res);
      pot_new[oidx + r] = res;
    }
  }
}

__global__ __launch_bounds__(256) void loss_kernel(
    const float* __restrict__ pot, const float* __restrict__ wx,
    const float* __restrict__ wy, float* __restrict__ out)
{
  const int tid = threadIdx.x;
  double acc = 0.0;
  for (int idx = tid; idx < NPOT; idx += 256) {
    acc += (double)wx[idx] * ((double)pot[0 * NPOT + idx] - (double)pot[2 * NPOT + idx]);
    acc += (double)wy[idx] * ((double)pot[1 * NPOT + idx] - (double)pot[3 * NPOT + idx]);
  }
  #pragma unroll
  for (int off = 32; off >= 1; off >>= 1)
    acc += __shfl_xor(acc, off, 64);
  __shared__ double wsum[4];
  if ((tid & 63) == 0) wsum[tid >> 6] = acc;
  __syncthreads();
  if (tid == 0)
    out[0] = (float)((wsum[0] + wsum[1] + wsum[2] + wsum[3]) / (double)BATCH);
}

extern "C" void kernel_launch(void* const* d_in, const int* in_sizes, int n_in,
                              void* d_out, int out_size, void* d_ws, size_t ws_size,
                              hipStream_t stream)
{
  const float* x  = (const float*)d_in[0];
  const float* y  = (const float*)d_in[1];
  const float* wx = (const float*)d_in[2];
  const float* wy = (const float*)d_in[3];

  const size_t potBytes = (size_t)2 * 4 * NPOT * 4;   // 524,288
  int n_mats = 0;
  if      (ws_size >= 4 * MAT_BYTES + potBytes) n_mats = 4;
  else if (ws_size >= 3 * MAT_BYTES + potBytes) n_mats = 3;
  else if (ws_size >= 2 * MAT_BYTES + potBytes) n_mats = 2;
  else if (ws_size >= 1 * MAT_BYTES + potBytes) n_mats = 1;

  unsigned int* mats = (unsigned int*)d_ws;
  float* pot[2];
  pot[0] = (float*)((char*)d_ws + (size_t)n_mats * MAT_BYTES);
  pot[1] = pot[0] + 4 * NPOT;

  // geomloss epsilon_schedule(p=2, diameter=3.15, blur=0.01, scaling=0.5)
  double eps_list[16]; int ne = 0;
  eps_list[ne++] = 3.15 * 3.15;
  const double stop = 2.0 * log(0.01), step = 2.0 * log(0.5);
  for (double e = 2.0 * log(3.15); e > stop; e += step) eps_list[ne++] = exp(e);
  eps_list[ne++] = 0.01 * 0.01;   // ne == 11

  const double LOG2E = 1.4426950408889634;
  const double PI    = 3.14159265358979323846;
  // acos(d) ~= sqrt(u)*(b0 + b1 u + b2 u^2 + b3 u^3), u = 1-d, |err|<=6.7e-5
  const double b0 = 1.4141461, b1 = 0.1197803, b2 = 0.0180731, b3 = 0.0187293;
  const double cdiag = 2.0 * acos(1.0 - 1e-6);   // exact diag cost 2.8284e-3
  const dim3 grid(1024), blkPass(512), blkLoss(256);
  int cur = 0;

  // ---- fused init pass: computes + stores u8 mats, writes pot[1] ----
  {
    const double e  = eps_list[0];
    const double S2 = 2.0 * 255.0 / PI;
    const double sc = 2.0 * LOG2E / e;
    const double kd = (PI / 255.0) * (LOG2E / e);
    const double efac = exp(-cdiag / e) - exp(-PI / e);
    const double ldf  = log(efac) * LOG2E;
    hipLaunchKernelGGL(sink_init_fused, grid, blkPass, 0, stream,
        x, y, wx, wy, mats, n_mats, pot[1 - cur],
        (float)e, (float)kd, (float)ldf,
        (float)(b0 * S2), (float)(b1 * S2), (float)(b2 * S2), (float)(b3 * S2),
        (float)(b0 * sc), (float)(b1 * sc), (float)(b2 * sc), (float)(b3 * sc));
    cur ^= 1;
  }

  auto launch_pass = [&](double e, int avg) {
    const double sc = 2.0 * LOG2E / e;
    const double kd = (PI / 255.0) * (LOG2E / e);
    const double efac = exp(-cdiag / e) - exp(-PI / e);
    const double ldf  = log(efac) * LOG2E;
    hipLaunchKernelGGL(sink_pass_r14, grid, blkPass, 0, stream,
        x, y, wx, wy, mats, n_mats, pot[cur], pot[1 - cur],
        (float)e, (float)(LOG2E / e), (float)(-LOG2E / e),
        (float)kd, (float)ldf,
        (float)(b0 * sc), (float)(b1 * sc), (float)(b2 * sc), (float)(b3 * sc), avg);
    cur ^= 1;
  };

  // annealing loop, averaging update
  for (int k = 0; k < ne; ++k)
    launch_pass(eps_list[k], 1);
  // final extrapolation, replace-mode
  launch_pass(eps_list[ne - 1], 0);

  hipLaunchKernelGGL(loss_kernel, dim3(1), blkLoss, 0, stream,
      pot[cur], wx, wy, (float*)d_out);
}